// Round 16
// baseline (1135.445 us; speedup 1.0000x reference)
//
#include <hip/hip_runtime.h>

#define CD 128   // channels
#define KK 9     // 3x3 kernel taps
#define NMASK 512

typedef __bf16 bf16x8 __attribute__((ext_vector_type(8)));
typedef float  f32x4  __attribute__((ext_vector_type(4)));
typedef float  f32x16 __attribute__((ext_vector_type(16)));

typedef __attribute__((address_space(1))) const void* gas_ptr;
typedef __attribute__((address_space(3))) void*       las_ptr;

// ---------------------------------------------------------------------------
// Prep kernel: blocks 0..17 transpose+cast W (tile via LDS); blocks 18+ do
// the linear feats f32->bf16 cast (fb16 doubles as conv2's residual source).
// ---------------------------------------------------------------------------
#define CAST_BLOCKS 2030
__global__ __launch_bounds__(256) void prep_kernel(
    const float* __restrict__ feats, unsigned short* __restrict__ fb16,
    const float* __restrict__ W1, const float* __restrict__ W2,
    unsigned short* __restrict__ W1T, unsigned short* __restrict__ W2T,
    const long total8) {
    if (blockIdx.x < 2 * KK) {
        __shared__ unsigned short tile[128 * 129];
        const int b = blockIdx.x;            // 0..17
        const int k = (b < KK) ? b : b - KK;
        const float* src = ((b < KK) ? W1 : W2) + k * (CD * CD);
        unsigned short* dst = ((b < KK) ? W1T : W2T) + k * (CD * CD);
        #pragma unroll 4
        for (int p = 0; p < 64; ++p) {
            int idx = p * 256 + threadIdx.x;     // coalesced read W[k][c][o]
            int c = idx >> 7, o = idx & 127;
            __bf16 h = (__bf16)src[idx];
            tile[o * 129 + c] = __builtin_bit_cast(unsigned short, h);
        }
        __syncthreads();
        #pragma unroll 4
        for (int p = 0; p < 64; ++p) {
            int idx = p * 256 + threadIdx.x;     // coalesced write W_T[k][o][c]
            int o = idx >> 7, c = idx & 127;
            dst[idx] = tile[o * 129 + c];
        }
    } else {
        const long stride = (long)CAST_BLOCKS * 256;
        for (long i = (long)(blockIdx.x - 2 * KK) * 256 + threadIdx.x;
             i < total8; i += stride) {
            f32x4 lo = *(const f32x4*)(feats + i * 8);
            f32x4 hi = *(const f32x4*)(feats + i * 8 + 4);
            bf16x8 v;
            #pragma unroll
            for (int e = 0; e < 4; ++e) {
                v[e]     = (__bf16)lo[e];
                v[e + 4] = (__bf16)hi[e];
            }
            *(bf16x8*)(fb16 + i * 8) = v;
        }
    }
}

// ---------------------------------------------------------------------------
// Validity-mask counting sort: group sites by 9-bit tap-validity mask so
// blocks share masks and can skip taps with NO valid site (block-union
// set-bit loop). perm varies run-to-run (atomics) but per-site outputs are
// independent of grouping (skipped taps contribute exactly +-0) -> output
// deterministic.
// ---------------------------------------------------------------------------
__global__ void zero_hist(int* hist) { hist[threadIdx.x] = 0; }

__global__ __launch_bounds__(256) void maskhist_kernel(
    const int* __restrict__ nbr, unsigned short* __restrict__ maskarr,
    int* __restrict__ hist, const int n) {
    const int s = blockIdx.x * 256 + threadIdx.x;
    if (s < n) {
        unsigned m = 0;
        #pragma unroll
        for (int k = 0; k < KK; ++k) {
            const int idx = nbr[(size_t)s * KK + k];
            if ((unsigned)idx < (unsigned)n) m |= 1u << k;
        }
        maskarr[s] = (unsigned short)m;
        atomicAdd(&hist[m], 1);
    }
}

__global__ __launch_bounds__(512) void scan_kernel(
    const int* __restrict__ hist, int* __restrict__ cnt,
    int* __restrict__ perm, const int n, const int padded) {
    __shared__ int base[NMASK];
    if (threadIdx.x == 0) {
        int acc = 0;
        for (int i = 0; i < NMASK; ++i) { base[i] = acc; acc += hist[i]; }
    }
    __syncthreads();
    if (threadIdx.x < NMASK) cnt[threadIdx.x] = base[threadIdx.x];
    for (int i = n + threadIdx.x; i < padded; i += 512) perm[i] = n - 1;
}

__global__ __launch_bounds__(256) void scatter_kernel(
    const unsigned short* __restrict__ maskarr, int* __restrict__ cnt,
    int* __restrict__ perm, const int n) {
    const int s = blockIdx.x * 256 + threadIdx.x;
    if (s < n) {
        const int pos = atomicAdd(&cnt[maskarr[s]], 1);
        perm[pos] = s;
    }
}

// ---------------------------------------------------------------------------
// Conv body = EXACT R13 K-loop structure (205us champion) + sparsity
// compaction: block processes 256 perm-ordered slots; tap loop iterates
// only over the block-union validity mask's set bits (~3.2 of 9 on
// average after the sort). Per tap: A-gathers at top, next-set-tap nbr +
// weight staging, MFMA, barrier. Weights double-buffered 2x32KB LDS via
// global_load_lds w=16, XOR swizzle on GLOBAL source (linear LDS dest),
// same XOR on ds_read. 2 waves/SIMD (register ceiling for this shape --
// R11/R14/R15 all spilled trying to exceed it).
// conv2: in-place residual epilogue (adjacent read+write), bf16 resid.
// ---------------------------------------------------------------------------
template <bool FIRST>
__device__ __forceinline__ void conv_body(
    const unsigned short* __restrict__ asrc,   // bf16 A source [n][128]
    const unsigned short* __restrict__ resid,  // bf16 residual (!FIRST)
    const unsigned short* __restrict__ WT,     // bf16 W_T[k][o][c] linear
    const int* __restrict__ nbr,               // [n][9]
    const int* __restrict__ perm,              // padded permutation
    const unsigned short* __restrict__ maskarr,// per-site validity mask
    unsigned short* __restrict__ hout,         // bf16 out (FIRST)
    float* __restrict__ fout,                  // f32 out (!FIRST)
    const int n, char (*wbuf)[32768])
{
    __shared__ int pblock[256];
    __shared__ int bmask_sh;

    const int tid  = threadIdx.x;
    const int lane = tid & 63;
    const int l31  = lane & 31;
    const int kh   = lane >> 5;
    const int wave = tid >> 6;

    if (tid == 0) bmask_sh = 0;
    __syncthreads();
    const int slot = blockIdx.x * 256 + tid;
    const int ps = perm[slot];                 // padding -> n-1 (valid site)
    pblock[tid] = ps;
    atomicOr(&bmask_sh, (int)maskarr[ps]);
    __syncthreads();
    unsigned bm = (unsigned)bmask_sh;          // bit 4 (center) always set

    const int site0 = pblock[wave * 64 + l31];
    const int site1 = pblock[wave * 64 + 32 + l31];

    auto stage = [&](int b, int k) {
        const char* tap = (const char*)(WT + (size_t)k * CD * CD);
        char* lb = &wbuf[b][0];
        #pragma unroll
        for (int i = 0; i < 8; ++i) {
            const int chunk = (i * 4 + wave) * 1024;
            const int d = chunk + lane * 16;
            const int s = d ^ (((d >> 8) & 7) << 4);
            __builtin_amdgcn_global_load_lds((gas_ptr)(tap + s),
                                             (las_ptr)(lb + chunk), 16, 0, 0);
        }
    };

    f32x16 acc[2][4];
    #pragma unroll
    for (int m = 0; m < 2; ++m)
        #pragma unroll
        for (int nf = 0; nf < 4; ++nf)
            #pragma unroll
            for (int i = 0; i < 16; ++i) acc[m][nf][i] = 0.f;

    bf16x8 zed;
    #pragma unroll
    for (int e = 0; e < 8; ++e) zed[e] = (__bf16)0.f;

    // prologue: first set tap
    int kcur = __builtin_ctz(bm); bm &= bm - 1;
    int c0 = nbr[(size_t)site0 * KK + kcur];
    int c1 = nbr[(size_t)site1 * KK + kcur];
    stage(0, kcur);
    __syncthreads();

    const int swq = (l31 & 7) << 4;
    int buf = 0;

    #pragma unroll 1
    while (true) {
        const bool haveNext = (bm != 0);
        int knext = 0;
        if (haveNext) { knext = __builtin_ctz(bm); bm &= bm - 1; }

        const bool v0 = (unsigned)c0 < (unsigned)n;
        const bool v1 = (unsigned)c1 < (unsigned)n;
        const size_t rr0 = (size_t)(v0 ? c0 : 0) * CD;
        const size_t rr1 = (size_t)(v1 ? c1 : 0) * CD;

        // ---- A phase (needed this tap) ----
        bf16x8 a0[8], a1[8];
        #pragma unroll
        for (int cs = 0; cs < 8; ++cs) {
            const int coff = cs * 16 + kh * 8;
            a0[cs] = *(const bf16x8*)(asrc + rr0 + coff);
            a1[cs] = *(const bf16x8*)(asrc + rr1 + coff);
            a0[cs] = v0 ? a0[cs] : zed;
            a1[cs] = v1 ? a1[cs] : zed;
        }

        // ---- next-set-tap prefetches (indices + weights) ----
        int n0 = 0, n1 = 0;
        if (haveNext) {
            n0 = nbr[(size_t)site0 * KK + knext];
            n1 = nbr[(size_t)site1 * KK + knext];
            stage(buf ^ 1, knext);
        }

        // ---- MFMA phase: B from LDS (swizzled) ----
        const char* wb = &wbuf[buf][0];
        #pragma unroll
        for (int cs = 0; cs < 8; ++cs) {
            #pragma unroll
            for (int nf = 0; nf < 4; ++nf) {
                const int x = ((nf * 32 + l31) << 8) + (cs << 5) + (kh << 4);
                bf16x8 b = *(const bf16x8*)(wb + (x ^ swq));
                acc[0][nf] = __builtin_amdgcn_mfma_f32_32x32x16_bf16(a0[cs], b, acc[0][nf], 0, 0, 0);
                acc[1][nf] = __builtin_amdgcn_mfma_f32_32x32x16_bf16(a1[cs], b, acc[1][nf], 0, 0, 0);
            }
        }

        __syncthreads();
        if (!haveNext) break;
        c0 = n0; c1 = n1; buf ^= 1;
    }

    // Epilogue: slot-guarded, perm-indirected rows. conv2: residual add in
    // place (adjacent read+write of the same out line).
    #pragma unroll
    for (int m = 0; m < 2; ++m) {
        #pragma unroll
        for (int rg = 0; rg < 16; ++rg) {
            const int row   = (rg & 3) + 8 * (rg >> 2) + 4 * kh;
            const int lslot = wave * 64 + m * 32 + row;
            if (blockIdx.x * 256 + lslot < n) {
                const int srow = pblock[lslot];
                #pragma unroll
                for (int nf = 0; nf < 4; ++nf) {
                    float v = acc[m][nf][rg];
                    const size_t oi = (size_t)srow * CD + nf * 32 + l31;
                    if (FIRST) {
                        v = v > 0.f ? v : 0.f;
                        hout[oi] = __builtin_bit_cast(unsigned short, (__bf16)v);
                    } else {
                        const __bf16 rb = __builtin_bit_cast(__bf16, resid[oi]);
                        v += (float)rb;
                        v = v > 0.f ? v : 0.f;
                        fout[oi] = v;
                    }
                }
            }
        }
    }
}

__global__ __launch_bounds__(256, 2) void conv1_kernel(
    const unsigned short* __restrict__ fb16,
    const unsigned short* __restrict__ WT,
    const int* __restrict__ nbr,
    const int* __restrict__ perm,
    const unsigned short* __restrict__ maskarr,
    unsigned short* __restrict__ hout,
    const int n)
{
    __shared__ __align__(16) char wbuf[2][32768];
    conv_body<true>(fb16, nullptr, WT, nbr, perm, maskarr, hout, nullptr, n, wbuf);
}

__global__ __launch_bounds__(256, 2) void conv2_kernel(
    const unsigned short* __restrict__ hid,
    const unsigned short* __restrict__ fb16,   // bf16 residual source
    const unsigned short* __restrict__ WT,
    const int* __restrict__ nbr,
    const int* __restrict__ perm,
    const unsigned short* __restrict__ maskarr,
    float* __restrict__ fout,
    const int n)
{
    __shared__ __align__(16) char wbuf[2][32768];
    conv_body<false>(hid, fb16, WT, nbr, perm, maskarr, nullptr, fout, n, wbuf);
}

extern "C" void kernel_launch(void* const* d_in, const int* in_sizes, int n_in,
                              void* d_out, int out_size, void* d_ws, size_t ws_size,
                              hipStream_t stream) {
    const float* feats = (const float*)d_in[0];
    const int*   nbr   = (const int*)d_in[1];
    const float* W1    = (const float*)d_in[2];
    const float* W2    = (const float*)d_in[3];
    float* out = (float*)d_out;

    const int n = in_sizes[0] / CD;   // active sites (200000)
    const int grid = (n + 255) / 256;
    const int padded = grid * 256;

    // workspace: hid, W1T, W2T, fb16 (u16), then maskarr (u16), perm, hist,
    // cnt (int). All rebuilt every launch (hist zeroed) -> replay-safe.
    unsigned short* hid  = (unsigned short*)d_ws;
    unsigned short* W1T  = hid + (size_t)n * CD;
    unsigned short* W2T  = W1T + KK * CD * CD;
    unsigned short* fb16 = W2T + KK * CD * CD;
    unsigned short* maskarr = fb16 + (size_t)n * CD;
    int* perm = (int*)(maskarr + ((n + 1) & ~1));
    int* hist = perm + padded;
    int* cnt  = hist + NMASK;
    (void)ws_size;

    const long total8 = (long)n * CD / 8;

    zero_hist<<<1, NMASK, 0, stream>>>(hist);
    prep_kernel<<<2 * KK + CAST_BLOCKS, 256, 0, stream>>>(
        feats, fb16, W1, W2, W1T, W2T, total8);
    maskhist_kernel<<<grid, 256, 0, stream>>>(nbr, maskarr, hist, n);
    scan_kernel<<<1, 512, 0, stream>>>(hist, cnt, perm, n, padded);
    scatter_kernel<<<grid, 256, 0, stream>>>(maskarr, cnt, perm, n);

    conv1_kernel<<<grid, 256, 0, stream>>>(fb16, W1T, nbr, perm, maskarr, hid, n);
    conv2_kernel<<<grid, 256, 0, stream>>>(hid, fb16, W2T, nbr, perm, maskarr, out, n);
}

// Round 17
// 229.966 us; speedup vs baseline: 4.9375x; 4.9375x over previous
//
#include <hip/hip_runtime.h>

#define CD 128   // channels
#define KK 9     // 3x3 kernel taps
#define NMASK 512

typedef __bf16 bf16x8 __attribute__((ext_vector_type(8)));
typedef float  f32x4  __attribute__((ext_vector_type(4)));
typedef float  f32x16 __attribute__((ext_vector_type(16)));

typedef __attribute__((address_space(1))) const void* gas_ptr;
typedef __attribute__((address_space(3))) void*       las_ptr;

// ---------------------------------------------------------------------------
// Prep kernel: blocks 0..17 transpose+cast W (tile via LDS); blocks 18+ do
// the linear feats f32->bf16 cast (fb16 doubles as conv2's residual source).
// ---------------------------------------------------------------------------
#define CAST_BLOCKS 2030
__global__ __launch_bounds__(256) void prep_kernel(
    const float* __restrict__ feats, unsigned short* __restrict__ fb16,
    const float* __restrict__ W1, const float* __restrict__ W2,
    unsigned short* __restrict__ W1T, unsigned short* __restrict__ W2T,
    const long total8) {
    if (blockIdx.x < 2 * KK) {
        __shared__ unsigned short tile[128 * 129];
        const int b = blockIdx.x;            // 0..17
        const int k = (b < KK) ? b : b - KK;
        const float* src = ((b < KK) ? W1 : W2) + k * (CD * CD);
        unsigned short* dst = ((b < KK) ? W1T : W2T) + k * (CD * CD);
        #pragma unroll 4
        for (int p = 0; p < 64; ++p) {
            int idx = p * 256 + threadIdx.x;     // coalesced read W[k][c][o]
            int c = idx >> 7, o = idx & 127;
            __bf16 h = (__bf16)src[idx];
            tile[o * 129 + c] = __builtin_bit_cast(unsigned short, h);
        }
        __syncthreads();
        #pragma unroll 4
        for (int p = 0; p < 64; ++p) {
            int idx = p * 256 + threadIdx.x;     // coalesced write W_T[k][o][c]
            int o = idx >> 7, c = idx & 127;
            dst[idx] = tile[o * 129 + c];
        }
    } else {
        const long stride = (long)CAST_BLOCKS * 256;
        for (long i = (long)(blockIdx.x - 2 * KK) * 256 + threadIdx.x;
             i < total8; i += stride) {
            f32x4 lo = *(const f32x4*)(feats + i * 8);
            f32x4 hi = *(const f32x4*)(feats + i * 8 + 4);
            bf16x8 v;
            #pragma unroll
            for (int e = 0; e < 4; ++e) {
                v[e]     = (__bf16)lo[e];
                v[e + 4] = (__bf16)hi[e];
            }
            *(bf16x8*)(fb16 + i * 8) = v;
        }
    }
}

// ---------------------------------------------------------------------------
// Validity-mask counting sort, CONTENTION-FREE (R16 lesson: 200k global
// atomics on a 32-line histogram = ~458us of line-serialized updates).
// Two-level: per-block LDS histogram -> <=1 global atomic per nonzero bin
// per block (~94k spread atomics, parallel). Scatter reserves a per-block
// range per mask and places sites at base+rank. Grouping preserved; only
// intra-bucket order varies (run-to-run), which no per-site output depends
// on (skipped taps contribute exactly +-0) -> output deterministic.
// ---------------------------------------------------------------------------
__global__ void zero_hist(int* hist) { hist[threadIdx.x] = 0; }

__global__ __launch_bounds__(256) void maskhist_kernel(
    const int* __restrict__ nbr, unsigned short* __restrict__ maskarr,
    int* __restrict__ hist, const int n) {
    __shared__ int lh[NMASK];
    for (int i = threadIdx.x; i < NMASK; i += 256) lh[i] = 0;
    __syncthreads();
    const int s = blockIdx.x * 256 + threadIdx.x;
    if (s < n) {
        unsigned m = 0;
        #pragma unroll
        for (int k = 0; k < KK; ++k) {
            const int idx = nbr[(size_t)s * KK + k];
            if ((unsigned)idx < (unsigned)n) m |= 1u << k;
        }
        maskarr[s] = (unsigned short)m;
        atomicAdd(&lh[m], 1);           // LDS atomic: cheap
    }
    __syncthreads();
    for (int i = threadIdx.x; i < NMASK; i += 256)
        if (lh[i]) atomicAdd(&hist[i], lh[i]);   // few, spread, parallel
}

__global__ __launch_bounds__(NMASK) void scan_kernel(
    const int* __restrict__ hist, int* __restrict__ cnt,
    int* __restrict__ perm, const int n, const int padded) {
    __shared__ int a[NMASK], b[NMASK];
    const int t = threadIdx.x;
    const int h = hist[t];
    a[t] = h;
    __syncthreads();
    int* src = a; int* dst = b;
    for (int off = 1; off < NMASK; off <<= 1) {   // Hillis-Steele inclusive
        dst[t] = src[t] + ((t >= off) ? src[t - off] : 0);
        __syncthreads();
        int* tmp = src; src = dst; dst = tmp;
    }
    cnt[t] = src[t] - h;                          // exclusive prefix
    for (int i = n + t; i < padded; i += NMASK) perm[i] = n - 1;
}

__global__ __launch_bounds__(256) void scatter_kernel(
    const unsigned short* __restrict__ maskarr, int* __restrict__ cnt,
    int* __restrict__ perm, const int n) {
    __shared__ int lh[NMASK];
    __shared__ int lbase[NMASK];
    for (int i = threadIdx.x; i < NMASK; i += 256) lh[i] = 0;
    __syncthreads();
    const int s = blockIdx.x * 256 + threadIdx.x;
    int m = 0, rank = 0;
    if (s < n) {
        m = maskarr[s];
        rank = atomicAdd(&lh[m], 1);    // LDS rank within block+mask
    }
    __syncthreads();
    for (int i = threadIdx.x; i < NMASK; i += 256)
        if (lh[i]) lbase[i] = atomicAdd(&cnt[i], lh[i]);  // reserve range
    __syncthreads();
    if (s < n) perm[lbase[m] + rank] = s;
}

// ---------------------------------------------------------------------------
// Conv body = EXACT R13 K-loop structure + sparsity compaction (unchanged
// from R16, which passed): block processes 256 perm-ordered slots; tap loop
// iterates only over the block-union validity mask's set bits (~3.2 of 9
// after the sort). Weights double-buffered 2x32KB LDS via global_load_lds
// w=16, XOR swizzle on GLOBAL source (linear LDS dest), same XOR on
// ds_read. 2 waves/SIMD (register ceiling: R11/R14/R15 spilled past it).
// conv2: in-place residual epilogue (adjacent read+write), bf16 resid.
// ---------------------------------------------------------------------------
template <bool FIRST>
__device__ __forceinline__ void conv_body(
    const unsigned short* __restrict__ asrc,   // bf16 A source [n][128]
    const unsigned short* __restrict__ resid,  // bf16 residual (!FIRST)
    const unsigned short* __restrict__ WT,     // bf16 W_T[k][o][c] linear
    const int* __restrict__ nbr,               // [n][9]
    const int* __restrict__ perm,              // padded permutation
    const unsigned short* __restrict__ maskarr,// per-site validity mask
    unsigned short* __restrict__ hout,         // bf16 out (FIRST)
    float* __restrict__ fout,                  // f32 out (!FIRST)
    const int n, char (*wbuf)[32768])
{
    __shared__ int pblock[256];
    __shared__ int bmask_sh;

    const int tid  = threadIdx.x;
    const int lane = tid & 63;
    const int l31  = lane & 31;
    const int kh   = lane >> 5;
    const int wave = tid >> 6;

    if (tid == 0) bmask_sh = 0;
    __syncthreads();
    const int slot = blockIdx.x * 256 + tid;
    const int ps = perm[slot];                 // padding -> n-1 (valid site)
    pblock[tid] = ps;
    atomicOr(&bmask_sh, (int)maskarr[ps]);
    __syncthreads();
    unsigned bm = (unsigned)bmask_sh;          // bit 4 (center) always set

    const int site0 = pblock[wave * 64 + l31];
    const int site1 = pblock[wave * 64 + 32 + l31];

    auto stage = [&](int b, int k) {
        const char* tap = (const char*)(WT + (size_t)k * CD * CD);
        char* lb = &wbuf[b][0];
        #pragma unroll
        for (int i = 0; i < 8; ++i) {
            const int chunk = (i * 4 + wave) * 1024;
            const int d = chunk + lane * 16;
            const int s = d ^ (((d >> 8) & 7) << 4);
            __builtin_amdgcn_global_load_lds((gas_ptr)(tap + s),
                                             (las_ptr)(lb + chunk), 16, 0, 0);
        }
    };

    f32x16 acc[2][4];
    #pragma unroll
    for (int m = 0; m < 2; ++m)
        #pragma unroll
        for (int nf = 0; nf < 4; ++nf)
            #pragma unroll
            for (int i = 0; i < 16; ++i) acc[m][nf][i] = 0.f;

    bf16x8 zed;
    #pragma unroll
    for (int e = 0; e < 8; ++e) zed[e] = (__bf16)0.f;

    // prologue: first set tap
    int kcur = __builtin_ctz(bm); bm &= bm - 1;
    int c0 = nbr[(size_t)site0 * KK + kcur];
    int c1 = nbr[(size_t)site1 * KK + kcur];
    stage(0, kcur);
    __syncthreads();

    const int swq = (l31 & 7) << 4;
    int buf = 0;

    #pragma unroll 1
    while (true) {
        const bool haveNext = (bm != 0);
        int knext = 0;
        if (haveNext) { knext = __builtin_ctz(bm); bm &= bm - 1; }

        const bool v0 = (unsigned)c0 < (unsigned)n;
        const bool v1 = (unsigned)c1 < (unsigned)n;
        const size_t rr0 = (size_t)(v0 ? c0 : 0) * CD;
        const size_t rr1 = (size_t)(v1 ? c1 : 0) * CD;

        // ---- A phase (needed this tap) ----
        bf16x8 a0[8], a1[8];
        #pragma unroll
        for (int cs = 0; cs < 8; ++cs) {
            const int coff = cs * 16 + kh * 8;
            a0[cs] = *(const bf16x8*)(asrc + rr0 + coff);
            a1[cs] = *(const bf16x8*)(asrc + rr1 + coff);
            a0[cs] = v0 ? a0[cs] : zed;
            a1[cs] = v1 ? a1[cs] : zed;
        }

        // ---- next-set-tap prefetches (indices + weights) ----
        int n0 = 0, n1 = 0;
        if (haveNext) {
            n0 = nbr[(size_t)site0 * KK + knext];
            n1 = nbr[(size_t)site1 * KK + knext];
            stage(buf ^ 1, knext);
        }

        // ---- MFMA phase: B from LDS (swizzled) ----
        const char* wb = &wbuf[buf][0];
        #pragma unroll
        for (int cs = 0; cs < 8; ++cs) {
            #pragma unroll
            for (int nf = 0; nf < 4; ++nf) {
                const int x = ((nf * 32 + l31) << 8) + (cs << 5) + (kh << 4);
                bf16x8 b = *(const bf16x8*)(wb + (x ^ swq));
                acc[0][nf] = __builtin_amdgcn_mfma_f32_32x32x16_bf16(a0[cs], b, acc[0][nf], 0, 0, 0);
                acc[1][nf] = __builtin_amdgcn_mfma_f32_32x32x16_bf16(a1[cs], b, acc[1][nf], 0, 0, 0);
            }
        }

        __syncthreads();
        if (!haveNext) break;
        c0 = n0; c1 = n1; buf ^= 1;
    }

    // Epilogue: slot-guarded, perm-indirected rows. conv2: residual add in
    // place (adjacent read+write of the same out line).
    #pragma unroll
    for (int m = 0; m < 2; ++m) {
        #pragma unroll
        for (int rg = 0; rg < 16; ++rg) {
            const int row   = (rg & 3) + 8 * (rg >> 2) + 4 * kh;
            const int lslot = wave * 64 + m * 32 + row;
            if (blockIdx.x * 256 + lslot < n) {
                const int srow = pblock[lslot];
                #pragma unroll
                for (int nf = 0; nf < 4; ++nf) {
                    float v = acc[m][nf][rg];
                    const size_t oi = (size_t)srow * CD + nf * 32 + l31;
                    if (FIRST) {
                        v = v > 0.f ? v : 0.f;
                        hout[oi] = __builtin_bit_cast(unsigned short, (__bf16)v);
                    } else {
                        const __bf16 rb = __builtin_bit_cast(__bf16, resid[oi]);
                        v += (float)rb;
                        v = v > 0.f ? v : 0.f;
                        fout[oi] = v;
                    }
                }
            }
        }
    }
}

__global__ __launch_bounds__(256, 2) void conv1_kernel(
    const unsigned short* __restrict__ fb16,
    const unsigned short* __restrict__ WT,
    const int* __restrict__ nbr,
    const int* __restrict__ perm,
    const unsigned short* __restrict__ maskarr,
    unsigned short* __restrict__ hout,
    const int n)
{
    __shared__ __align__(16) char wbuf[2][32768];
    conv_body<true>(fb16, nullptr, WT, nbr, perm, maskarr, hout, nullptr, n, wbuf);
}

__global__ __launch_bounds__(256, 2) void conv2_kernel(
    const unsigned short* __restrict__ hid,
    const unsigned short* __restrict__ fb16,   // bf16 residual source
    const unsigned short* __restrict__ WT,
    const int* __restrict__ nbr,
    const int* __restrict__ perm,
    const unsigned short* __restrict__ maskarr,
    float* __restrict__ fout,
    const int n)
{
    __shared__ __align__(16) char wbuf[2][32768];
    conv_body<false>(hid, fb16, WT, nbr, perm, maskarr, nullptr, fout, n, wbuf);
}

extern "C" void kernel_launch(void* const* d_in, const int* in_sizes, int n_in,
                              void* d_out, int out_size, void* d_ws, size_t ws_size,
                              hipStream_t stream) {
    const float* feats = (const float*)d_in[0];
    const int*   nbr   = (const int*)d_in[1];
    const float* W1    = (const float*)d_in[2];
    const float* W2    = (const float*)d_in[3];
    float* out = (float*)d_out;

    const int n = in_sizes[0] / CD;   // active sites (200000)
    const int grid = (n + 255) / 256;
    const int padded = grid * 256;

    // workspace: hid, W1T, W2T, fb16 (u16), then maskarr (u16), perm, hist,
    // cnt (int). All rebuilt every launch (hist zeroed) -> replay-safe.
    unsigned short* hid  = (unsigned short*)d_ws;
    unsigned short* W1T  = hid + (size_t)n * CD;
    unsigned short* W2T  = W1T + KK * CD * CD;
    unsigned short* fb16 = W2T + KK * CD * CD;
    unsigned short* maskarr = fb16 + (size_t)n * CD;
    int* perm = (int*)(maskarr + ((n + 1) & ~1));
    int* hist = perm + padded;
    int* cnt  = hist + NMASK;
    (void)ws_size;

    const long total8 = (long)n * CD / 8;

    zero_hist<<<1, NMASK, 0, stream>>>(hist);
    prep_kernel<<<2 * KK + CAST_BLOCKS, 256, 0, stream>>>(
        feats, fb16, W1, W2, W1T, W2T, total8);
    maskhist_kernel<<<grid, 256, 0, stream>>>(nbr, maskarr, hist, n);
    scan_kernel<<<1, NMASK, 0, stream>>>(hist, cnt, perm, n, padded);
    scatter_kernel<<<grid, 256, 0, stream>>>(maskarr, cnt, perm, n);

    conv1_kernel<<<grid, 256, 0, stream>>>(fb16, W1T, nbr, perm, maskarr, hid, n);
    conv2_kernel<<<grid, 256, 0, stream>>>(hid, fb16, W2T, nbr, perm, maskarr, out, n);
}

// Round 18
// 205.689 us; speedup vs baseline: 5.5202x; 1.1180x over previous
//
#include <hip/hip_runtime.h>

#define CD 128   // channels
#define KK 9     // 3x3 kernel taps

typedef __bf16 bf16x8 __attribute__((ext_vector_type(8)));
typedef float  f32x4  __attribute__((ext_vector_type(4)));
typedef float  f32x16 __attribute__((ext_vector_type(16)));

typedef __attribute__((address_space(1))) const void* gas_ptr;
typedef __attribute__((address_space(3))) void*       las_ptr;

// ---------------------------------------------------------------------------
// Prep kernel: blocks 0..17 transpose+cast W (tile via LDS); blocks 18+ do
// the linear feats f32->bf16 cast (fb16 doubles as conv2's residual source:
// 51MB, L3-resident — R13 verified this cuts conv2 FETCH 120->95MB).
// ---------------------------------------------------------------------------
#define CAST_BLOCKS 2030
__global__ __launch_bounds__(256) void prep_kernel(
    const float* __restrict__ feats, unsigned short* __restrict__ fb16,
    const float* __restrict__ W1, const float* __restrict__ W2,
    unsigned short* __restrict__ W1T, unsigned short* __restrict__ W2T,
    const long total8) {
    if (blockIdx.x < 2 * KK) {
        __shared__ unsigned short tile[128 * 129];
        const int b = blockIdx.x;            // 0..17
        const int k = (b < KK) ? b : b - KK;
        const float* src = ((b < KK) ? W1 : W2) + k * (CD * CD);
        unsigned short* dst = ((b < KK) ? W1T : W2T) + k * (CD * CD);
        #pragma unroll 4
        for (int p = 0; p < 64; ++p) {
            int idx = p * 256 + threadIdx.x;     // coalesced read W[k][c][o]
            int c = idx >> 7, o = idx & 127;
            __bf16 h = (__bf16)src[idx];
            tile[o * 129 + c] = __builtin_bit_cast(unsigned short, h);
        }
        __syncthreads();
        #pragma unroll 4
        for (int p = 0; p < 64; ++p) {
            int idx = p * 256 + threadIdx.x;     // coalesced write W_T[k][o][c]
            int o = idx >> 7, c = idx & 127;
            dst[idx] = tile[o * 129 + c];
        }
    } else {
        const long stride = (long)CAST_BLOCKS * 256;
        for (long i = (long)(blockIdx.x - 2 * KK) * 256 + threadIdx.x;
             i < total8; i += stride) {
            f32x4 lo = *(const f32x4*)(feats + i * 8);
            f32x4 hi = *(const f32x4*)(feats + i * 8 + 4);
            bf16x8 v;
            #pragma unroll
            for (int e = 0; e < 4; ++e) {
                v[e]     = (__bf16)lo[e];
                v[e + 4] = (__bf16)hi[e];
            }
            *(bf16x8*)(fb16 + i * 8) = v;
        }
    }
}

// ---------------------------------------------------------------------------
// Shared conv body — the R13 champion (205us total: conv1@~68, conv2@~105).
// Wave = 64 sites x 128 out, 256-thr block, 2 waves/SIMD (register-pinned:
// acc 128 AGPR + ~128 VGPR = 256/wave vs the 512/SIMD pool; R7/R11/R14/R15
// all spilled trying to exceed it). Weights double-buffered 2x32KB LDS via
// global_load_lds w=16 + XOR swizzle on the GLOBAL source (linear LDS
// dest), same XOR on ds_read. nbr prefetched one tap ahead; A-gathers
// batched at tap top. Epilogue does the residual add IN PLACE (adjacent
// read+write of each out line -> single clean L2 writeback; hoisting the
// read costs +27MB FETCH / +48MB WRITE via cold-line write-allocate —
// R10/R12). Residual source = fb16 (bf16, L3-resident — R13). Tap-skip
// compaction is a measured null (R17): the kernel is valid-gather-bound,
// not instruction-bound.
// ---------------------------------------------------------------------------
template <bool FIRST>
__device__ __forceinline__ void conv_body(
    const unsigned short* __restrict__ asrc,   // bf16 A source [n][128]
    const unsigned short* __restrict__ resid,  // bf16 residual (!FIRST)
    const unsigned short* __restrict__ WT,     // bf16 W_T[k][o][c] linear
    const int* __restrict__ nbr,               // [n][9]
    unsigned short* __restrict__ hout,         // bf16 out (FIRST)
    float* __restrict__ fout,                  // f32 out (!FIRST)
    const int n, char (*wbuf)[32768])
{
    const int tid  = threadIdx.x;
    const int lane = tid & 63;
    const int l31  = lane & 31;
    const int kh   = lane >> 5;
    const int wave = tid >> 6;
    const int base = blockIdx.x * 256 + wave * 64;
    const int s0 = base + l31;
    const int s1 = base + 32 + l31;
    const int sc0 = (s0 < n) ? s0 : (n - 1);
    const int sc1 = (s1 < n) ? s1 : (n - 1);

    auto stage = [&](int b, int k) {
        const char* tap = (const char*)(WT + (size_t)k * CD * CD);
        char* lb = &wbuf[b][0];
        #pragma unroll
        for (int i = 0; i < 8; ++i) {
            const int chunk = (i * 4 + wave) * 1024;
            const int d = chunk + lane * 16;
            const int s = d ^ (((d >> 8) & 7) << 4);
            __builtin_amdgcn_global_load_lds((gas_ptr)(tap + s),
                                             (las_ptr)(lb + chunk), 16, 0, 0);
        }
    };

    f32x16 acc[2][4];
    #pragma unroll
    for (int m = 0; m < 2; ++m)
        #pragma unroll
        for (int nf = 0; nf < 4; ++nf)
            #pragma unroll
            for (int i = 0; i < 16; ++i) acc[m][nf][i] = 0.f;

    bf16x8 zed;
    #pragma unroll
    for (int e = 0; e < 8; ++e) zed[e] = (__bf16)0.f;

    int c0 = nbr[(size_t)sc0 * KK];
    int c1 = nbr[(size_t)sc1 * KK];
    stage(0, 0);
    __syncthreads();

    const int swq = (l31 & 7) << 4;

    #pragma unroll 1
    for (int k = 0; k < KK; ++k) {
        const bool v0 = (unsigned)c0 < (unsigned)n;
        const bool v1 = (unsigned)c1 < (unsigned)n;
        const size_t rr0 = (size_t)(v0 ? c0 : 0) * CD;
        const size_t rr1 = (size_t)(v1 ? c1 : 0) * CD;

        // ---- A phase first (needed this tap) ----
        bf16x8 a0[8], a1[8];
        #pragma unroll
        for (int cs = 0; cs < 8; ++cs) {
            const int coff = cs * 16 + kh * 8;
            a0[cs] = *(const bf16x8*)(asrc + rr0 + coff);
            a1[cs] = *(const bf16x8*)(asrc + rr1 + coff);
            a0[cs] = v0 ? a0[cs] : zed;
            a1[cs] = v1 ? a1[cs] : zed;
        }

        // ---- next-tap prefetches (indices + weights) ----
        int n0 = 0, n1 = 0;
        if (k + 1 < KK) {
            n0 = nbr[(size_t)sc0 * KK + k + 1];
            n1 = nbr[(size_t)sc1 * KK + k + 1];
            stage((k + 1) & 1, k + 1);
        }

        // ---- MFMA phase: B from LDS (swizzled) ----
        const char* wb = &wbuf[k & 1][0];
        #pragma unroll
        for (int cs = 0; cs < 8; ++cs) {
            #pragma unroll
            for (int nf = 0; nf < 4; ++nf) {
                const int x = ((nf * 32 + l31) << 8) + (cs << 5) + (kh << 4);
                bf16x8 b = *(const bf16x8*)(wb + (x ^ swq));
                acc[0][nf] = __builtin_amdgcn_mfma_f32_32x32x16_bf16(a0[cs], b, acc[0][nf], 0, 0, 0);
                acc[1][nf] = __builtin_amdgcn_mfma_f32_32x32x16_bf16(a1[cs], b, acc[1][nf], 0, 0, 0);
            }
        }

        __syncthreads();
        c0 = n0; c1 = n1;
    }

    // Epilogue: residual add in place (adjacent read+write of each out line)
    #pragma unroll
    for (int m = 0; m < 2; ++m) {
        #pragma unroll
        for (int rg = 0; rg < 16; ++rg) {
            const int row  = (rg & 3) + 8 * (rg >> 2) + 4 * kh;
            const int srow = base + m * 32 + row;
            if (srow < n) {
                #pragma unroll
                for (int nf = 0; nf < 4; ++nf) {
                    float v = acc[m][nf][rg];
                    const size_t oi = (size_t)srow * CD + nf * 32 + l31;
                    if (FIRST) {
                        v = v > 0.f ? v : 0.f;
                        hout[oi] = __builtin_bit_cast(unsigned short, (__bf16)v);
                    } else {
                        const __bf16 rb = __builtin_bit_cast(__bf16, resid[oi]);
                        v += (float)rb;
                        v = v > 0.f ? v : 0.f;
                        fout[oi] = v;
                    }
                }
            }
        }
    }
}

__global__ __launch_bounds__(256, 2) void conv1_kernel(
    const unsigned short* __restrict__ fb16,
    const unsigned short* __restrict__ WT,
    const int* __restrict__ nbr,
    unsigned short* __restrict__ hout,
    const int n)
{
    __shared__ __align__(16) char wbuf[2][32768];
    conv_body<true>(fb16, nullptr, WT, nbr, hout, nullptr, n, wbuf);
}

__global__ __launch_bounds__(256, 2) void conv2_kernel(
    const unsigned short* __restrict__ hid,
    const unsigned short* __restrict__ fb16,   // bf16 residual source
    const unsigned short* __restrict__ WT,
    const int* __restrict__ nbr,
    float* __restrict__ fout,
    const int n)
{
    __shared__ __align__(16) char wbuf[2][32768];
    conv_body<false>(hid, fb16, WT, nbr, nullptr, fout, n, wbuf);
}

extern "C" void kernel_launch(void* const* d_in, const int* in_sizes, int n_in,
                              void* d_out, int out_size, void* d_ws, size_t ws_size,
                              hipStream_t stream) {
    const float* feats = (const float*)d_in[0];
    const int*   nbr   = (const int*)d_in[1];
    const float* W1    = (const float*)d_in[2];
    const float* W2    = (const float*)d_in[3];
    float* out = (float*)d_out;

    const int n = in_sizes[0] / CD;   // active sites (200000)

    // workspace layout: hid [n][128] bf16, W1T, W2T, fbf16 [n][128] bf16
    unsigned short* hid  = (unsigned short*)d_ws;
    unsigned short* W1T  = hid + (size_t)n * CD;
    unsigned short* W2T  = W1T + KK * CD * CD;
    unsigned short* fb16 = W2T + KK * CD * CD;
    (void)ws_size;

    const long total8 = (long)n * CD / 8;
    prep_kernel<<<2 * KK + CAST_BLOCKS, 256, 0, stream>>>(
        feats, fb16, W1, W2, W1T, W2T, total8);

    const int grid = (n + 255) / 256;   // 256 sites per 4-wave block
    conv1_kernel<<<grid, 256, 0, stream>>>(fb16, W1T, nbr, hid, n);
    conv2_kernel<<<grid, 256, 0, stream>>>(hid, fb16, W2T, nbr, out, n);
}